// Round 9
// baseline (396.534 us; speedup 1.0000x reference)
//
#include <hip/hip_runtime.h>
#include <hip/hip_bf16.h>
#include <stdint.h>

typedef _Float16 half8 __attribute__((ext_vector_type(8)));
typedef __attribute__((ext_vector_type(8))) short short8;
typedef __attribute__((ext_vector_type(4))) float floatx4;
typedef __attribute__((ext_vector_type(4))) uint32_t uint32x4;

#define GROUP_SZ 128

__device__ __forceinline__ uint32_t cvt_pk_f16(float lo, float hi) {
    uint32_t r;
    asm("v_cvt_pkrtz_f16_f32 %0, %1, %2" : "=v"(r) : "v"(lo), "v"(hi));
    return r;
}
__device__ __forceinline__ uint32_t pk_add_f16(uint32_t a, uint32_t b) {
    uint32_t r;
    asm("v_pk_add_f16 %0, %1, %2" : "=v"(r) : "v"(a), "v"(b));
    return r;
}
__device__ __forceinline__ uint32_t pk_mul_f16(uint32_t a, uint32_t b) {
    uint32_t r;
    asm("v_pk_mul_f16 %0, %1, %2" : "=v"(r) : "v"(a), "v"(b));
    return r;
}

// ============================== prepass: A fp32 -> f16 plain [M][K] ==========
__global__ __launch_bounds__(256)
void convA_kernel(const float* __restrict__ x, uint4* __restrict__ aws, int total8) {
    int idx = blockIdx.x * 256 + threadIdx.x;
    if (idx >= total8) return;
    const float4* xp = reinterpret_cast<const float4*>(x) + (size_t)idx * 2;
    float4 a = xp[0], b = xp[1];
    uint4 o;
    o.x = cvt_pk_f16(a.x, a.y);
    o.y = cvt_pk_f16(a.z, a.w);
    o.z = cvt_pk_f16(b.x, b.y);
    o.w = cvt_pk_f16(b.z, b.w);
    aws[idx] = o;
}

// ==== prepass: dequant B -> f16 tiled slot-major [nt][kt64][h][slot][row][16B]
__global__ __launch_bounds__(256)
void deqB_kernel(const int* __restrict__ qw, const float* __restrict__ sc,
                 const int* __restrict__ qz, char* __restrict__ bws, int K, int N) {
    const int n = blockIdx.x * 256 + threadIdx.x;
    const int wk = blockIdx.y;               // word-row: 8 k's
    if (n >= N) return;
    const uint32_t w = (uint32_t)qw[(size_t)wk * N + n];
    const int g = wk >> 4;                   // k/128
    const float s = sc[(size_t)g * N + n];
    const uint32_t zw = (uint32_t)qz[(size_t)g * (N >> 3) + (n >> 3)];
    const float zf = -(float)(1025u + ((zw >> ((n & 7) * 4)) & 15u));
    const uint32_t c2 = cvt_pk_f16(zf, zf);
    const uint32_t s2 = cvt_pk_f16(s, s);
    uint32_t oo[4];
    #pragma unroll
    for (int i = 0; i < 4; ++i) {
        const uint32_t tt = w >> (8 * i);
        const uint32_t qi = ((tt & 0xFu) | 0x64006400u) | ((tt << 12) & 0xF0000u);
        oo[i] = pk_mul_f16(pk_add_f16(qi, c2), s2);
    }
    uint4 o; o.x = oo[0]; o.y = oo[1]; o.z = oo[2]; o.w = oo[3];
    const int NKT = K >> 6;
    const int nt = n >> 8, h = (n >> 7) & 1, row = n & 127;
    const int kt = wk >> 3, slot = wk & 7;
    size_t off = ((((size_t)nt * NKT + kt) * 2 + h) * 8 + slot) * 2048 + (size_t)row * 16;
    *reinterpret_cast<uint4*>(bws + off) = o;
}

// == main: 256x256 f16 GEMM, BK=128 — A via LDS (DMA), B direct global->reg ==
__global__ __launch_bounds__(512, 2)
void gemm8_kernel(const char* __restrict__ Aws, const char* __restrict__ Bws,
                  float* __restrict__ out, int M, int K, int N) {
    __shared__ char smem[131072];  // 2 bufs x A 64KB (BK=128)

    const int NT = K >> 7;         // 128-k tiles
    const int NKT64 = K >> 6;      // 64-k sub-tiles (B layout granularity)
    const int nbm = M >> 8, nbn = N >> 8;
    const int nwg = nbm * nbn;
    int bid = blockIdx.x;
    int q = nwg >> 3, r = nwg & 7;
    int xcd = bid & 7, lin = bid >> 3;
    int sid = (xcd < r ? xcd * (q + 1) : r * (q + 1) + (xcd - r) * q) + lin;
    // bm-fast ordering: consecutive sids share the B panel (fits per-XCD L2)
    const int bm = sid % nbm, bn = sid / nbm;
    const int m0 = bm << 8, n0 = bn << 8;

    const int tid = threadIdx.x;
    const int lane = tid & 63, w = tid >> 6;
    const int wm = w >> 2, wn = w & 3;       // 2 x 4 waves
    const int fr = lane & 15, hi = lane >> 4;
    const int r8 = lane >> 3, c8 = lane & 7;

    // ---- A staging: uniform base + 32-bit per-lane offsets (pre-swizzled src) ----
    const uint32_t K2 = (uint32_t)K * 2;
    const char* aBase = Aws + (size_t)m0 * K2;
    uint32_t aOff[2][2];
    #pragma unroll
    for (int h = 0; h < 2; ++h)
        #pragma unroll
        for (int i = 0; i < 2; ++i)
            aOff[h][i] = (uint32_t)(h * 128 + w * 16 + i * 8 + r8) * K2
                       + (uint32_t)((c8 ^ r8) * 16);
    const char* bBase = Bws + (size_t)bn * ((size_t)NKT64 * 32768);

    // stage one 64KB A tile (BK=128) = 8 global_load_lds per thread
    auto stageA = [&](uint32_t buf, int kt) {
        #pragma unroll
        for (int kh = 0; kh < 2; ++kh)
            #pragma unroll
            for (int h = 0; h < 2; ++h)
                #pragma unroll
                for (int i = 0; i < 2; ++i) {
                    const char* src = aBase + aOff[h][i] + (uint32_t)(kt * 256 + kh * 128);
                    char* dst = smem + buf * 65536u + (uint32_t)kh * 32768u
                                     + (uint32_t)h * 16384u + (uint32_t)w * 2048u
                                     + (uint32_t)i * 1024u;
                    __builtin_amdgcn_global_load_lds(
                        (const __attribute__((address_space(1))) void*)src,
                        (__attribute__((address_space(3))) void*)dst, 16, 0, 0);
                }
    };

    // ---- accumulators / fragments ----
    floatx4 acc[8][4];
    const floatx4 fz = {0.f, 0.f, 0.f, 0.f};
    #pragma unroll
    for (int i = 0; i < 8; ++i)
        #pragma unroll
        for (int j = 0; j < 4; ++j) acc[i][j] = fz;
    half8 af_a[4][2], af_b[4][2];   // QM0 / QM1 A fragments (from LDS)
    half8 bf_x[2][2], bf_y[2][2];   // QN0 / QN1 B fragments (from global)

#define LOAD_AF(AF, QM, AS) { _Pragma("unroll") for (int fmi = 0; fmi < 4; ++fmi) { \
    _Pragma("unroll") for (int kk = 0; kk < 2; ++kk) { \
        uint32_t row = (uint32_t)(wm * 128 + ((QM) * 4 + fmi) * 16 + fr); \
        uint32_t p = (uint32_t)((kk * 4 + hi) ^ (fr & 7)); \
        uint32x4 u = *reinterpret_cast<const uint32x4*>((AS) + row * 128u + p * 16u); \
        AF[fmi][kk] = __builtin_bit_cast(half8, u); } } }

// B fragment straight from global (prepass slot-major layout, per-lane 16B)
#define LOAD_BFG(BF, QN, KT64) { _Pragma("unroll") for (int fnj = 0; fnj < 2; ++fnj) { \
    _Pragma("unroll") for (int kk = 0; kk < 2; ++kk) { \
        uint32_t nl = (uint32_t)(wn * 64 + ((QN) * 2 + fnj) * 16 + fr); \
        uint32_t slot = (uint32_t)(kk * 4 + hi); \
        size_t off = ((size_t)((KT64) * 2 + (int)(nl >> 7)) * 8 + slot) * 2048 \
                   + (size_t)(nl & 127u) * 16u; \
        uint32x4 u = *reinterpret_cast<const uint32x4*>(bBase + off); \
        BF[fnj][kk] = __builtin_bit_cast(half8, u); } } }

// kk OUTER: 8 independent MFMAs per k-slice
#define MM(AF, BF, QM, QN) { _Pragma("unroll") for (int kk = 0; kk < 2; ++kk) \
    _Pragma("unroll") for (int fmi = 0; fmi < 4; ++fmi) \
    _Pragma("unroll") for (int fnj = 0; fnj < 2; ++fnj) \
        acc[(QM) * 4 + fmi][(QN) * 2 + fnj] = __builtin_amdgcn_mfma_f32_16x16x32_f16( \
            AF[fmi][kk], BF[fnj][kk], acc[(QM) * 4 + fmi][(QN) * 2 + fnj], 0, 0, 0); }

    // ---- prologue: A(0), A(1) staged; B(kt64=0) to regs ----
    stageA(0, 0);
    if (NT > 1) stageA(1, 1);
    LOAD_BFG(bf_x, 0, 0);
    LOAD_BFG(bf_y, 1, 0);
    if (NT > 1) { asm volatile("s_waitcnt vmcnt(16)" ::: "memory"); }
    else        { asm volatile("s_waitcnt vmcnt(8)" ::: "memory"); }
    __builtin_amdgcn_s_barrier();

    for (int t = 0; t < NT; ++t) {
        const uint32_t c = (uint32_t)(t & 1);
        const char* As0 = smem + c * 65536u;
        const char* As1 = As0 + 32768u;
        const bool st1 = (t + 1 < NT);
        const bool st2 = (t + 2 < NT);
        // ======== half 0 (k 0..63 of tile): consumes bf(2t), reloads bf(2t+1) ====
        LOAD_AF(af_a, 0, As0);
        LOAD_AF(af_b, 1, As0);
        __builtin_amdgcn_s_setprio(1);
        MM(af_a, bf_x, 0, 0);
        MM(af_b, bf_x, 1, 0);
        __builtin_amdgcn_s_setprio(0);
        LOAD_BFG(bf_x, 0, 2 * t + 1);
        __builtin_amdgcn_s_setprio(1);
        MM(af_a, bf_y, 0, 1);
        MM(af_b, bf_y, 1, 1);
        __builtin_amdgcn_s_setprio(0);
        LOAD_BFG(bf_y, 1, 2 * t + 1);
        // ======== half 1 (k 64..127): same buffer, no barrier needed ============
        LOAD_AF(af_a, 0, As1);
        LOAD_AF(af_b, 1, As1);
        __builtin_amdgcn_s_setprio(1);
        MM(af_a, bf_x, 0, 0);
        MM(af_b, bf_x, 1, 0);
        __builtin_amdgcn_s_setprio(0);
        if (st1) LOAD_BFG(bf_x, 0, 2 * t + 2);
        __builtin_amdgcn_s_setprio(1);
        MM(af_a, bf_y, 0, 1);
        MM(af_b, bf_y, 1, 1);
        __builtin_amdgcn_s_setprio(0);
        if (st1) LOAD_BFG(bf_y, 1, 2 * t + 2);
        // barrier 1: all waves done reading buf c -> safe to overwrite via DMA
        __builtin_amdgcn_s_barrier();
        if (st2) {
            stageA(c, t + 2);
            // outstanding: A(t+1)[8] bf(t+1,h0)[8] A(t+2)[8] -> retire A(t+1)
            asm volatile("s_waitcnt vmcnt(16)" ::: "memory");
        } else if (st1) {
            asm volatile("s_waitcnt vmcnt(8)" ::: "memory");
        }
        // barrier 2: A(t+1) landed for all waves
        if (st1) __builtin_amdgcn_s_barrier();
    }
#undef LOAD_AF
#undef LOAD_BFG
#undef MM

    // ---- epilogue: C/D layout col=lane&15, row=(lane>>4)*4+reg ----
    float* op = out + (size_t)(m0 + wm * 128) * N + n0 + wn * 64;
    #pragma unroll
    for (int fm = 0; fm < 8; ++fm)
        #pragma unroll
        for (int fn = 0; fn < 4; ++fn)
            #pragma unroll
            for (int rr = 0; rr < 4; ++rr)
                op[(size_t)(fm * 16 + hi * 4 + rr) * N + fn * 16 + fr] = acc[fm][fn][rr];
}

// ================= fallback: fused 128x128 kernel (verified R1) ==============
__device__ __forceinline__ uint32_t cvt_pk_bf16(float lo, float hi) {
    uint32_t r;
    asm("v_cvt_pk_bf16_f32 %0, %1, %2" : "=v"(r) : "v"(lo), "v"(hi));
    return r;
}
__device__ __forceinline__ uint32_t fswz(uint32_t row, uint32_t byte_in_row) {
    return row * 128u + (byte_in_row ^ ((row & 7u) << 4));
}

__global__ __launch_bounds__(256, 2)
void fused128_kernel(const float* __restrict__ x, const int* __restrict__ qweight,
                     const float* __restrict__ scales, const int* __restrict__ qzeros,
                     float* __restrict__ out, int M, int K, int N) {
    __shared__ char smem[32768];
    char* Ald = smem;
    char* Bld = smem + 16384;
    const int nbm = M / 128, nbn = N / 128;
    const int nwg = nbm * nbn;
    int bid = blockIdx.x;
    int q = nwg >> 3, r = nwg & 7;
    int xcd = bid & 7, lin = bid >> 3;
    int sid = (xcd < r ? xcd * (q + 1) : r * (q + 1) + (xcd - r) * q) + lin;
    int bm = sid / nbn, bn = sid % nbn;
    const int m0 = bm * 128, n0 = bn * 128;
    const int t = threadIdx.x;
    const int lane = t & 63, wave = t >> 6;
    const int tm = t >> 4, tk4 = t & 15;
    const int sn = t & 127, kwh = t >> 7;
    const int gn = n0 + sn;
    const int NT = K / 64;
    float4 av[8]; uint32_t qw[4]; float sc; uint32_t zw;
    const float* xp = x + (size_t)(m0 + tm) * K + tk4 * 4;
    const int* qp = qweight + (size_t)(kwh * 4) * N + gn;
    auto load_tile = [&](int ts) {
        const int k0 = ts * 64;
        #pragma unroll
        for (int i = 0; i < 8; ++i)
            av[i] = *reinterpret_cast<const float4*>(xp + (size_t)i * 16 * K + k0);
        const int g = k0 >> 7;
        sc = scales[(size_t)g * N + gn];
        zw = (uint32_t)qzeros[(size_t)g * (N >> 3) + (gn >> 3)];
        const int* qb = qp + (size_t)(k0 >> 3) * N;
        #pragma unroll
        for (int j = 0; j < 4; ++j) qw[j] = (uint32_t)qb[(size_t)j * N];
    };
    const int zsh = (gn & 7) * 4;
    auto write_tile = [&]() {
        #pragma unroll
        for (int i = 0; i < 8; ++i) {
            uint2 p;
            p.x = cvt_pk_bf16(av[i].x, av[i].y);
            p.y = cvt_pk_bf16(av[i].z, av[i].w);
            *reinterpret_cast<uint2*>(Ald + fswz((uint32_t)(i * 16 + tm), (uint32_t)(tk4 * 8))) = p;
        }
        const float z = (float)((zw >> zsh) & 15u) + 1.0f;
        const float nz = -z * sc;
        #pragma unroll
        for (int j = 0; j < 4; ++j) {
            const uint32_t wv = qw[j];
            float f[8];
            #pragma unroll
            for (int e = 0; e < 8; ++e)
                f[e] = fmaf((float)((wv >> (4 * e)) & 15u), sc, nz);
            uint4 p;
            p.x = cvt_pk_bf16(f[0], f[1]); p.y = cvt_pk_bf16(f[2], f[3]);
            p.z = cvt_pk_bf16(f[4], f[5]); p.w = cvt_pk_bf16(f[6], f[7]);
            *reinterpret_cast<uint4*>(Bld + fswz((uint32_t)sn, (uint32_t)((kwh * 4 + j) * 16))) = p;
        }
    };
    floatx4 acc[4][4];
    const floatx4 fz = {0.f, 0.f, 0.f, 0.f};
    #pragma unroll
    for (int i = 0; i < 4; ++i)
        #pragma unroll
        for (int j = 0; j < 4; ++j) acc[i][j] = fz;
    const int wm = (wave >> 1) * 64, wn = (wave & 1) * 64;
    const int fr = lane & 15;
    const int fkb = ((lane >> 4) * 8) * 2;
    auto compute = [&]() {
        #pragma unroll
        for (int kk = 0; kk < 2; ++kk) {
            short8 afv[4], bfv[4];
            #pragma unroll
            for (int i = 0; i < 4; ++i)
                afv[i] = *reinterpret_cast<const short8*>(
                    Ald + fswz((uint32_t)(wm + i * 16 + fr), (uint32_t)(kk * 64 + fkb)));
            #pragma unroll
            for (int i = 0; i < 4; ++i)
                bfv[i] = *reinterpret_cast<const short8*>(
                    Bld + fswz((uint32_t)(wn + i * 16 + fr), (uint32_t)(kk * 64 + fkb)));
            #pragma unroll
            for (int i = 0; i < 4; ++i)
                #pragma unroll
                for (int j = 0; j < 4; ++j)
                    acc[i][j] = __builtin_amdgcn_mfma_f32_16x16x32_bf16(afv[i], bfv[j], acc[i][j], 0, 0, 0);
        }
    };
    load_tile(0);
    write_tile();
    __syncthreads();
    for (int ts = 0; ts < NT; ++ts) {
        if (ts + 1 < NT) load_tile(ts + 1);
        compute();
        __syncthreads();
        if (ts + 1 < NT) write_tile();
        __syncthreads();
    }
    const int fq = lane >> 4;
    float* op = out + (size_t)(m0 + wm) * N + n0 + wn;
    #pragma unroll
    for (int i = 0; i < 4; ++i)
        #pragma unroll
        for (int j = 0; j < 4; ++j)
            #pragma unroll
            for (int rr = 0; rr < 4; ++rr)
                op[(size_t)(i * 16 + fq * 4 + rr) * N + j * 16 + fr] = acc[i][j][rr];
}

// ============================================================================
extern "C" void kernel_launch(void* const* d_in, const int* in_sizes, int n_in,
                              void* d_out, int out_size, void* d_ws, size_t ws_size,
                              hipStream_t stream) {
    const float* x       = (const float*)d_in[0];
    const int*   qweight = (const int*)d_in[1];
    const float* scales  = (const float*)d_in[2];
    const int*   qzeros  = (const int*)d_in[3];

    const int K = in_sizes[4];
    const int M = in_sizes[0] / K;
    const int G = K / GROUP_SZ;
    const int N = in_sizes[2] / G;
    float* out = (float*)d_out;

    const size_t needA = (size_t)M * K * 2;
    const size_t needB = (size_t)K * (size_t)N * 2;
    const bool ok = (ws_size >= needA + needB) && (M % 256 == 0) && (N % 256 == 0)
                    && (K % 256 == 0) && (N % 8 == 0);
    if (ok) {
        char* aws = (char*)d_ws;
        char* bws = aws + needA;
        const int total8 = M * (K / 8);
        hipLaunchKernelGGL(convA_kernel, dim3((total8 + 255) / 256), dim3(256), 0, stream,
                           x, (uint4*)aws, total8);
        hipLaunchKernelGGL(deqB_kernel, dim3((N + 255) / 256, K / 8), dim3(256), 0, stream,
                           qweight, scales, qzeros, bws, K, N);
        hipLaunchKernelGGL(gemm8_kernel, dim3((M / 256) * (N / 256)), dim3(512), 0, stream,
                           aws, bws, out, M, K, N);
    } else {
        const int nwg = (M / 128) * (N / 128);
        hipLaunchKernelGGL(fused128_kernel, dim3(nwg), dim3(256), 0, stream,
                           x, qweight, scales, qzeros, out, M, K, N);
    }
}

// Round 10
// 385.194 us; speedup vs baseline: 1.0294x; 1.0294x over previous
//
#include <hip/hip_runtime.h>
#include <hip/hip_bf16.h>
#include <stdint.h>

typedef _Float16 half8 __attribute__((ext_vector_type(8)));
typedef __attribute__((ext_vector_type(8))) short short8;
typedef __attribute__((ext_vector_type(4))) float floatx4;
typedef __attribute__((ext_vector_type(4))) uint32_t uint32x4;

#define GROUP_SZ 128

__device__ __forceinline__ uint32_t cvt_pk_f16(float lo, float hi) {
    uint32_t r;
    asm("v_cvt_pkrtz_f16_f32 %0, %1, %2" : "=v"(r) : "v"(lo), "v"(hi));
    return r;
}
__device__ __forceinline__ uint32_t pk_add_f16(uint32_t a, uint32_t b) {
    uint32_t r;
    asm("v_pk_add_f16 %0, %1, %2" : "=v"(r) : "v"(a), "v"(b));
    return r;
}
__device__ __forceinline__ uint32_t pk_mul_f16(uint32_t a, uint32_t b) {
    uint32_t r;
    asm("v_pk_mul_f16 %0, %1, %2" : "=v"(r) : "v"(a), "v"(b));
    return r;
}

// ============================== prepass: A fp32 -> f16 plain [M][K] ==========
__global__ __launch_bounds__(256)
void convA_kernel(const float* __restrict__ x, uint4* __restrict__ aws, int total8) {
    int idx = blockIdx.x * 256 + threadIdx.x;
    if (idx >= total8) return;
    const float4* xp = reinterpret_cast<const float4*>(x) + (size_t)idx * 2;
    float4 a = xp[0], b = xp[1];
    uint4 o;
    o.x = cvt_pk_f16(a.x, a.y);
    o.y = cvt_pk_f16(a.z, a.w);
    o.z = cvt_pk_f16(b.x, b.y);
    o.w = cvt_pk_f16(b.z, b.w);
    aws[idx] = o;
}

// ==== prepass: dequant B -> f16 tiled slot-major [nt][kt64][h][slot][row][16B]
__global__ __launch_bounds__(256)
void deqB_kernel(const int* __restrict__ qw, const float* __restrict__ sc,
                 const int* __restrict__ qz, char* __restrict__ bws, int K, int N) {
    const int n = blockIdx.x * 256 + threadIdx.x;
    const int wk = blockIdx.y;               // word-row: 8 k's
    if (n >= N) return;
    const uint32_t w = (uint32_t)qw[(size_t)wk * N + n];
    const int g = wk >> 4;                   // k/128
    const float s = sc[(size_t)g * N + n];
    const uint32_t zw = (uint32_t)qz[(size_t)g * (N >> 3) + (n >> 3)];
    const float zf = -(float)(1025u + ((zw >> ((n & 7) * 4)) & 15u));
    const uint32_t c2 = cvt_pk_f16(zf, zf);
    const uint32_t s2 = cvt_pk_f16(s, s);
    uint32_t oo[4];
    #pragma unroll
    for (int i = 0; i < 4; ++i) {
        const uint32_t tt = w >> (8 * i);
        const uint32_t qi = ((tt & 0xFu) | 0x64006400u) | ((tt << 12) & 0xF0000u);
        oo[i] = pk_mul_f16(pk_add_f16(qi, c2), s2);
    }
    uint4 o; o.x = oo[0]; o.y = oo[1]; o.z = oo[2]; o.w = oo[3];
    const int NKT = K >> 6;
    const int nt = n >> 8, h = (n >> 7) & 1, row = n & 127;
    const int kt = wk >> 3, slot = wk & 7;
    size_t off = ((((size_t)nt * NKT + kt) * 2 + h) * 8 + slot) * 2048 + (size_t)row * 16;
    *reinterpret_cast<uint4*>(bws + off) = o;
}

// == main: 256x256 f16 GEMM (BK=64) — strength-reduced addressing ===========
__global__ __launch_bounds__(512, 2)
void gemm8_kernel(const char* __restrict__ Aws, const char* __restrict__ Bws,
                  float* __restrict__ out, int M, int K, int N) {
    __shared__ char smem[65536];   // 2 bufs x A 32KB

    const int NT = K >> 6;
    const int nbm = M >> 8, nbn = N >> 8;
    const int nwg = nbm * nbn;
    int bid = blockIdx.x;
    int q = nwg >> 3, r = nwg & 7;
    int xcd = bid & 7, lin = bid >> 3;
    int sid = (xcd < r ? xcd * (q + 1) : r * (q + 1) + (xcd - r) * q) + lin;
    // bm-fast ordering: consecutive sids share the B panel (fits per-XCD L2)
    const int bm = sid % nbm, bn = sid / nbm;
    const int m0 = bm << 8, n0 = bn << 8;

    const int tid = threadIdx.x;
    const int lane = tid & 63, w = tid >> 6;
    const int wm = w >> 2, wn = w & 3;       // 2 x 4 waves
    const int fr = lane & 15, hi = lane >> 4;
    const int r8 = lane >> 3, c8 = lane & 7;
    const uint32_t wOff = (uint32_t)w * 2048u;

    // ---- A DMA source: 4 running pointers (advance +128 per staged tile) ----
    const uint32_t K2 = (uint32_t)K * 2;
    const char* aBase = Aws + (size_t)m0 * K2;
    const char* aPtr[2][2];
    #pragma unroll
    for (int h = 0; h < 2; ++h)
        #pragma unroll
        for (int i = 0; i < 2; ++i)
            aPtr[h][i] = aBase + (size_t)((uint32_t)(h * 128 + w * 16 + i * 8 + r8) * K2
                                          + (uint32_t)((c8 ^ r8) * 16));

    // ---- B fragment source: 2 running pointers (advance +32768 per tile) ----
    // frag (qn,fnj) folds into imm offset qn*512+fnj*256 ((nl>>7) wave-constant)
    const char* bBase = Bws + (size_t)bn * ((size_t)NT * 32768);
    const int nl0 = wn * 64 + fr;
    const char* bP[2];
    #pragma unroll
    for (int kk = 0; kk < 2; ++kk)
        bP[kk] = bBase + (size_t)(((uint32_t)(nl0 >> 7) * 8 + (uint32_t)(kk * 4 + hi)) * 2048u
                                  + (uint32_t)(nl0 & 127) * 16u);

    // ---- A LDS read bases: 2 per-lane offsets; (qm,fmi) fold into ds imm ----
    uint32_t aRdK[2];
    #pragma unroll
    for (int kk = 0; kk < 2; ++kk)
        aRdK[kk] = (uint32_t)(wm * 128 + fr) * 128u
                 + (uint32_t)(((kk * 4 + hi) ^ (fr & 7)) * 16);

    auto stageA = [&](uint32_t cOff) {
        #pragma unroll
        for (int h = 0; h < 2; ++h)
            #pragma unroll
            for (int i = 0; i < 2; ++i) {
                char* dst = smem + (cOff + wOff + (uint32_t)(h * 16384 + i * 1024));
                __builtin_amdgcn_global_load_lds(
                    (const __attribute__((address_space(1))) void*)aPtr[h][i],
                    (__attribute__((address_space(3))) void*)dst, 16, 0, 0);
                aPtr[h][i] += 128;
            }
    };

    // ---- accumulators / fragments ----
    floatx4 acc[8][4];
    const floatx4 fz = {0.f, 0.f, 0.f, 0.f};
    #pragma unroll
    for (int i = 0; i < 8; ++i)
        #pragma unroll
        for (int j = 0; j < 4; ++j) acc[i][j] = fz;
    half8 af_a[4][2], af_b[4][2];   // QM0 / QM1 A fragments (from LDS)
    half8 bf_x[2][2], bf_y[2][2];   // QN0 / QN1 B fragments (from global)

// A fragment reads: base VGPR + compile-time immediate (qm*8192 + fmi*2048)
#define LOAD_AF(AF, QM, ABASE) { _Pragma("unroll") for (int fmi = 0; fmi < 4; ++fmi) { \
    _Pragma("unroll") for (int kk = 0; kk < 2; ++kk) { \
        uint32x4 u = *reinterpret_cast<const uint32x4*>( \
            (ABASE) + aRdK[kk] + (uint32_t)((QM) * 8192 + fmi * 2048)); \
        AF[fmi][kk] = __builtin_bit_cast(half8, u); } } }

// B fragment loads: running pointer + compile-time immediate (qn*512 + fnj*256)
#define LOAD_BFG(BF, QN) { _Pragma("unroll") for (int fnj = 0; fnj < 2; ++fnj) { \
    _Pragma("unroll") for (int kk = 0; kk < 2; ++kk) { \
        uint32x4 u = *reinterpret_cast<const uint32x4*>( \
            bP[kk] + (uint32_t)((QN) * 512 + fnj * 256)); \
        BF[fnj][kk] = __builtin_bit_cast(half8, u); } } }

#define ADV_BP() { bP[0] += 32768; bP[1] += 32768; }

// kk OUTER: 8 independent MFMAs per k-slice
#define MM(AF, BF, QM, QN) { _Pragma("unroll") for (int kk = 0; kk < 2; ++kk) \
    _Pragma("unroll") for (int fmi = 0; fmi < 4; ++fmi) \
    _Pragma("unroll") for (int fnj = 0; fnj < 2; ++fnj) \
        acc[(QM) * 4 + fmi][(QN) * 2 + fnj] = __builtin_amdgcn_mfma_f32_16x16x32_f16( \
            AF[fmi][kk], BF[fnj][kk], acc[(QM) * 4 + fmi][(QN) * 2 + fnj], 0, 0, 0); }

    // ---- prologue: A(0)->buf0, A(1)->buf1; B(0) to regs ----
    stageA(0);
    if (NT > 1) stageA(32768u);
    LOAD_BFG(bf_x, 0);
    LOAD_BFG(bf_y, 1);
    ADV_BP();
    if (NT > 1) { asm volatile("s_waitcnt vmcnt(12)" ::: "memory"); }
    else        { asm volatile("s_waitcnt vmcnt(8)" ::: "memory"); }
    __builtin_amdgcn_s_barrier();

    for (int t = 0; t < NT; ++t) {
        const uint32_t cOff = (uint32_t)(t & 1) * 32768u;
        const char* As = smem + cOff;
        const bool st1 = (t + 1 < NT);
        const bool st2 = (t + 2 < NT);
        // A fragments for this tile (16 ds_read_b128, imm-folded)
        LOAD_AF(af_a, 0, As);
        LOAD_AF(af_b, 1, As);
        // clusters 1-2 consume bf_x, then reload bf_x <- B(t+1) qn0
        __builtin_amdgcn_s_setprio(1);
        MM(af_a, bf_x, 0, 0);
        MM(af_b, bf_x, 1, 0);
        __builtin_amdgcn_s_setprio(0);
        if (st1) LOAD_BFG(bf_x, 0);
        // clusters 3-4 consume bf_y, then reload bf_y <- B(t+1) qn1
        __builtin_amdgcn_s_setprio(1);
        MM(af_a, bf_y, 0, 1);
        MM(af_b, bf_y, 1, 1);
        __builtin_amdgcn_s_setprio(0);
        if (st1) { LOAD_BFG(bf_y, 1); ADV_BP(); }
        // barrier 1: all waves done reading buf c -> safe to overwrite via DMA
        __builtin_amdgcn_s_barrier();
        if (st2) {
            stageA(cOff);
            // outstanding: A(t+1)[4] bf(t+1)[8] A(t+2)[4] -> retire A(t+1)
            asm volatile("s_waitcnt vmcnt(12)" ::: "memory");
        } else if (st1) {
            asm volatile("s_waitcnt vmcnt(8)" ::: "memory");
        }
        // barrier 2: A(t+1) landed for all waves
        if (st1) __builtin_amdgcn_s_barrier();
    }
#undef LOAD_AF
#undef LOAD_BFG
#undef ADV_BP
#undef MM

    // ---- epilogue: C/D layout col=lane&15, row=(lane>>4)*4+reg ----
    float* op = out + (size_t)(m0 + wm * 128) * N + n0 + wn * 64;
    #pragma unroll
    for (int fm = 0; fm < 8; ++fm)
        #pragma unroll
        for (int fn = 0; fn < 4; ++fn)
            #pragma unroll
            for (int rr = 0; rr < 4; ++rr)
                op[(size_t)(fm * 16 + hi * 4 + rr) * N + fn * 16 + fr] = acc[fm][fn][rr];
}

// ================= fallback: fused 128x128 kernel (verified R1) ==============
__device__ __forceinline__ uint32_t cvt_pk_bf16(float lo, float hi) {
    uint32_t r;
    asm("v_cvt_pk_bf16_f32 %0, %1, %2" : "=v"(r) : "v"(lo), "v"(hi));
    return r;
}
__device__ __forceinline__ uint32_t fswz(uint32_t row, uint32_t byte_in_row) {
    return row * 128u + (byte_in_row ^ ((row & 7u) << 4));
}

__global__ __launch_bounds__(256, 2)
void fused128_kernel(const float* __restrict__ x, const int* __restrict__ qweight,
                     const float* __restrict__ scales, const int* __restrict__ qzeros,
                     float* __restrict__ out, int M, int K, int N) {
    __shared__ char smem[32768];
    char* Ald = smem;
    char* Bld = smem + 16384;
    const int nbm = M / 128, nbn = N / 128;
    const int nwg = nbm * nbn;
    int bid = blockIdx.x;
    int q = nwg >> 3, r = nwg & 7;
    int xcd = bid & 7, lin = bid >> 3;
    int sid = (xcd < r ? xcd * (q + 1) : r * (q + 1) + (xcd - r) * q) + lin;
    int bm = sid / nbn, bn = sid % nbn;
    const int m0 = bm * 128, n0 = bn * 128;
    const int t = threadIdx.x;
    const int lane = t & 63, wave = t >> 6;
    const int tm = t >> 4, tk4 = t & 15;
    const int sn = t & 127, kwh = t >> 7;
    const int gn = n0 + sn;
    const int NT = K / 64;
    float4 av[8]; uint32_t qw[4]; float sc; uint32_t zw;
    const float* xp = x + (size_t)(m0 + tm) * K + tk4 * 4;
    const int* qp = qweight + (size_t)(kwh * 4) * N + gn;
    auto load_tile = [&](int ts) {
        const int k0 = ts * 64;
        #pragma unroll
        for (int i = 0; i < 8; ++i)
            av[i] = *reinterpret_cast<const float4*>(xp + (size_t)i * 16 * K + k0);
        const int g = k0 >> 7;
        sc = scales[(size_t)g * N + gn];
        zw = (uint32_t)qzeros[(size_t)g * (N >> 3) + (gn >> 3)];
        const int* qb = qp + (size_t)(k0 >> 3) * N;
        #pragma unroll
        for (int j = 0; j < 4; ++j) qw[j] = (uint32_t)qb[(size_t)j * N];
    };
    const int zsh = (gn & 7) * 4;
    auto write_tile = [&]() {
        #pragma unroll
        for (int i = 0; i < 8; ++i) {
            uint2 p;
            p.x = cvt_pk_bf16(av[i].x, av[i].y);
            p.y = cvt_pk_bf16(av[i].z, av[i].w);
            *reinterpret_cast<uint2*>(Ald + fswz((uint32_t)(i * 16 + tm), (uint32_t)(tk4 * 8))) = p;
        }
        const float z = (float)((zw >> zsh) & 15u) + 1.0f;
        const float nz = -z * sc;
        #pragma unroll
        for (int j = 0; j < 4; ++j) {
            const uint32_t wv = qw[j];
            float f[8];
            #pragma unroll
            for (int e = 0; e < 8; ++e)
                f[e] = fmaf((float)((wv >> (4 * e)) & 15u), sc, nz);
            uint4 p;
            p.x = cvt_pk_bf16(f[0], f[1]); p.y = cvt_pk_bf16(f[2], f[3]);
            p.z = cvt_pk_bf16(f[4], f[5]); p.w = cvt_pk_bf16(f[6], f[7]);
            *reinterpret_cast<uint4*>(Bld + fswz((uint32_t)sn, (uint32_t)((kwh * 4 + j) * 16))) = p;
        }
    };
    floatx4 acc[4][4];
    const floatx4 fz = {0.f, 0.f, 0.f, 0.f};
    #pragma unroll
    for (int i = 0; i < 4; ++i)
        #pragma unroll
        for (int j = 0; j < 4; ++j) acc[i][j] = fz;
    const int wm = (wave >> 1) * 64, wn = (wave & 1) * 64;
    const int fr = lane & 15;
    const int fkb = ((lane >> 4) * 8) * 2;
    auto compute = [&]() {
        #pragma unroll
        for (int kk = 0; kk < 2; ++kk) {
            short8 afv[4], bfv[4];
            #pragma unroll
            for (int i = 0; i < 4; ++i)
                afv[i] = *reinterpret_cast<const short8*>(
                    Ald + fswz((uint32_t)(wm + i * 16 + fr), (uint32_t)(kk * 64 + fkb)));
            #pragma unroll
            for (int i = 0; i < 4; ++i)
                bfv[i] = *reinterpret_cast<const short8*>(
                    Bld + fswz((uint32_t)(wn + i * 16 + fr), (uint32_t)(kk * 64 + fkb)));
            #pragma unroll
            for (int i = 0; i < 4; ++i)
                #pragma unroll
                for (int j = 0; j < 4; ++j)
                    acc[i][j] = __builtin_amdgcn_mfma_f32_16x16x32_bf16(afv[i], bfv[j], acc[i][j], 0, 0, 0);
        }
    };
    load_tile(0);
    write_tile();
    __syncthreads();
    for (int ts = 0; ts < NT; ++ts) {
        if (ts + 1 < NT) load_tile(ts + 1);
        compute();
        __syncthreads();
        if (ts + 1 < NT) write_tile();
        __syncthreads();
    }
    const int fq = lane >> 4;
    float* op = out + (size_t)(m0 + wm) * N + n0 + wn;
    #pragma unroll
    for (int i = 0; i < 4; ++i)
        #pragma unroll
        for (int j = 0; j < 4; ++j)
            #pragma unroll
            for (int rr = 0; rr < 4; ++rr)
                op[(size_t)(i * 16 + fq * 4 + rr) * N + j * 16 + fr] = acc[i][j][rr];
}

// ============================================================================
extern "C" void kernel_launch(void* const* d_in, const int* in_sizes, int n_in,
                              void* d_out, int out_size, void* d_ws, size_t ws_size,
                              hipStream_t stream) {
    const float* x       = (const float*)d_in[0];
    const int*   qweight = (const int*)d_in[1];
    const float* scales  = (const float*)d_in[2];
    const int*   qzeros  = (const int*)d_in[3];

    const int K = in_sizes[4];
    const int M = in_sizes[0] / K;
    const int G = K / GROUP_SZ;
    const int N = in_sizes[2] / G;
    float* out = (float*)d_out;

    const size_t needA = (size_t)M * K * 2;
    const size_t needB = (size_t)K * (size_t)N * 2;
    const bool ok = (ws_size >= needA + needB) && (M % 256 == 0) && (N % 256 == 0)
                    && (K % 128 == 0) && (N % 8 == 0);
    if (ok) {
        char* aws = (char*)d_ws;
        char* bws = aws + needA;
        const int total8 = M * (K / 8);
        hipLaunchKernelGGL(convA_kernel, dim3((total8 + 255) / 256), dim3(256), 0, stream,
                           x, (uint4*)aws, total8);
        hipLaunchKernelGGL(deqB_kernel, dim3((N + 255) / 256, K / 8), dim3(256), 0, stream,
                           qweight, scales, qzeros, bws, K, N);
        hipLaunchKernelGGL(gemm8_kernel, dim3((M / 256) * (N / 256)), dim3(512), 0, stream,
                           aws, bws, out, M, K, N);
    } else {
        const int nwg = (M / 128) * (N / 128);
        hipLaunchKernelGGL(fused128_kernel, dim3(nwg), dim3(256), 0, stream,
                           x, qweight, scales, qzeros, out, M, K, N);
    }
}